// Round 5
// baseline (441.270 us; speedup 1.0000x reference)
//
#include <hip/hip_runtime.h>
#include <math.h>

#pragma clang fp contract(off)

#define NB 128
#define NA 8732
#define NC 21
#define TOPK 200
#define BCAP 512
#define CONF_T 0.01
#define NMS_T 0.045
#define NQ (NA / 4)   // 2183 float4 per class row
#define HSIZE 2048    // coarse buckets over f32 key bits [30:15]

// ---------------------------------------------------------------------------
// exact f64 masked softmax score, self-contained from conf (op order == np ref)
// ---------------------------------------------------------------------------
__device__ __forceinline__ double exact_score_cf(const float* __restrict__ conf,
                                                 int b, int i, int c) {
  const float* row = conf + ((size_t)b * NA + i) * NC;
  float r[NC];
#pragma unroll
  for (int k = 0; k < NC; ++k) r[k] = row[k];
  float mx = r[0];
#pragma unroll
  for (int k = 1; k < NC; ++k) mx = fmaxf(mx, r[k]);
  double d = 0.0;
#pragma unroll
  for (int k = 0; k < NC; ++k) d += exp((double)r[k] - (double)mx);
  double s = exp((double)r[c] - (double)mx) / d;
  return (s > CONF_T) ? s : 0.0;
}

__device__ __forceinline__ bool entBefore(double sa, int ia, double sb, int ib) {
  return (sa > sb) || (sa == sb && ia < ib);
}

// coarse bucket of an f32 score key; -1 = zero key. Monotone in key value.
// Keys live in (0.0099, 1]: x in [~67, 1792] -- clamps never active in range.
__device__ __forceinline__ int kbucket(unsigned key) {
  if (key == 0u) return -1;
  int x = (int)(key >> 15) - 0x7800;
  if (x < 1) x = 1;
  if (x > HSIZE - 1) x = HSIZE - 1;
  return x;
}

// ---------------------------------------------------------------------------
// k_prep: f32 softmax keys only (HW expf). Key error ~2e-6 rel << bucket width
// ~4e-3, so bucket order coarsens the exact f64 score order with margin; the
// {D-1,D,D+1} exact resolution in k_fast absorbs all key error. Mask relaxed
// to 0.0099 so f32 error cannot wrongly zero a key near 0.01 (sub-threshold
// selections resolve to exact 0 downstream -> zero rows, output-invisible).
// ---------------------------------------------------------------------------
__global__ __launch_bounds__(256) void k_prep(const float* __restrict__ conf,
                                              float* __restrict__ scores) {
  __shared__ float rows[256 * NC];
  int base = blockIdx.x * 256;                  // NB*NA == 4366*256 exactly
  const float4* src = (const float4*)(conf + (size_t)base * NC);
  float4* dst = (float4*)rows;
  for (int t = threadIdx.x; t < (256 * NC) / 4; t += 256) dst[t] = src[t];
  __syncthreads();
  int g = base + threadIdx.x;
  const float* row = rows + threadIdx.x * NC;   // stride 21: conflict-light
  float v[NC];
#pragma unroll
  for (int k = 0; k < NC; ++k) v[k] = row[k];
  float mx = v[0];
#pragma unroll
  for (int k = 1; k < NC; ++k) mx = fmaxf(mx, v[k]);
  float e[NC], s = 0.0f;
#pragma unroll
  for (int k = 0; k < NC; ++k) {
    e[k] = expf(v[k] - mx);
    s += e[k];
  }
  float inv = 1.0f / s;
  int b = g / NA, i = g - b * NA;
#pragma unroll
  for (int cc = 1; cc < NC; ++cc) {
    float sc = e[cc] * inv;
    scores[(size_t)(b * (NC - 1) + (cc - 1)) * NA + i] = (sc > 0.0099f) ? sc : 0.0f;
  }
}

// ---------------------------------------------------------------------------
// k_fast: one 256-thread block per (b,c), XCD-swizzled.
// ---------------------------------------------------------------------------
__global__ __launch_bounds__(256, 6) void k_fast(const float* __restrict__ loc,
                                                 const float* __restrict__ conf,
                                                 const float* __restrict__ anchors,
                                                 const float* __restrict__ scores,
                                                 float* __restrict__ out) {
  int id = blockIdx.x;
  int xcd = id & 7, slot = id >> 3;     // same-b classes share an XCD
  int c = slot % NC;
  int b = (slot / NC) * 8 + xcd;
  int tid = threadIdx.x;
  float* outbase = out + ((size_t)(b * NC + c)) * TOPK * 5;

  if (c == 0) {
    for (int k = tid; k < TOPK * 5; k += 256) outbase[k] = 0.0f;
    return;
  }

  union U1 {  // radix/collect phase vs box phase (disjoint in time)
    struct { unsigned hist[HSIZE]; unsigned chunk[256]; } r;  // 9216 B
    double dbox[TOPK][4];                                     // 6400 B
  };
  union U2 {  // boundary phase vs suppression phase (disjoint in time)
    struct { double bnds[BCAP]; int bndi[BCAP]; } bb;  // 6144 B
    unsigned supp[TOPK][9];  // stride 9 (coprime 32): conflict-free writes
  };
  __shared__ U1 u1;
  __shared__ U2 u2;
  __shared__ float4 fbox[TOPK];   // f32 shadow boxes (b128 broadcast reads)
  __shared__ float farea[TOPK];
  __shared__ double ssel[256];
  __shared__ int isel[256];
  __shared__ unsigned keepw[7];
  __shared__ int ctl_cnt, ctl_m, ctl_n1, ctl_kneed, ctl_lo, ctl_hi, ctl_k;
  __shared__ unsigned ctl_pref;

  const float4* sc4 =
      (const float4*)(scores + (size_t)(b * (NC - 1) + (c - 1)) * NA);

  // ---- single-pass coarse histogram (zeros skipped) ----
  for (int t = tid; t < HSIZE; t += 256) u1.r.hist[t] = 0u;
  if (tid == 0) { ctl_cnt = 0; ctl_m = 0; }
  __syncthreads();
  for (int q = tid; q < NQ; q += 256) {
    float4 k4 = sc4[q];
    unsigned kb[4] = {__float_as_uint(k4.x), __float_as_uint(k4.y),
                      __float_as_uint(k4.z), __float_as_uint(k4.w)};
#pragma unroll
    for (int t = 0; t < 4; ++t) {
      int idx = kbucket(kb[t]);
      if (idx >= 0) atomicAdd(&u1.r.hist[idx], 1u);
    }
  }
  __syncthreads();

  // ---- boundary buckets {D-1, D, D+1}; certain = buckets > D+1 ----
  {
    unsigned csum = 0;
#pragma unroll
    for (int j = 0; j < 8; ++j) csum += u1.r.hist[tid * 8 + j];
    u1.r.chunk[tid] = csum;
  }
  __syncthreads();
  if (tid == 0) {
    unsigned cum = 0;
    int tc = -1;
    for (int t = 255; t >= 0; --t) {
      unsigned h = u1.r.chunk[t];
      if (cum + h >= (unsigned)TOPK) { tc = t; break; }
      cum += h;
    }
    if (tc < 0) {  // sparse: fewer than 200 nonzero keys
      ctl_lo = 1; ctl_hi = 0; ctl_n1 = (int)cum; ctl_kneed = TOPK - (int)cum;
    } else {
      int D = tc * 8;
      for (int j = 7; j >= 0; --j) {
        unsigned h = u1.r.hist[tc * 8 + j];
        if (cum + h >= (unsigned)TOPK) { D = tc * 8 + j; break; }
        cum += h;
      }
      int hi = (D + 1 < HSIZE) ? D + 1 : D;
      int lo = (D - 1 >= 1) ? D - 1 : D;
      unsigned hup = (hi > D) ? u1.r.hist[hi] : 0u;
      ctl_lo = lo; ctl_hi = hi;
      ctl_n1 = (int)(cum - hup);        // count(buckets > hi)
      ctl_kneed = TOPK - ctl_n1;
    }
  }
  __syncthreads();
  int lo = ctl_lo, hi = ctl_hi, n1 = ctl_n1, kneed = ctl_kneed;

  // ---- collect: certain (bucket > hi) and boundary (lo..hi) ----
  for (int q = tid; q < NQ; q += 256) {
    float4 k4 = sc4[q];
    unsigned kb[4] = {__float_as_uint(k4.x), __float_as_uint(k4.y),
                      __float_as_uint(k4.z), __float_as_uint(k4.w)};
#pragma unroll
    for (int t = 0; t < 4; ++t) {
      int idx = kbucket(kb[t]);
      if (idx < 0) continue;
      if (idx > hi) {
        int p = atomicAdd(&ctl_cnt, 1);
        if (p < 256) isel[p] = q * 4 + t;      // exactly n1 <= 199 entries
      } else if (idx >= lo) {
        int p = atomicAdd(&ctl_m, 1);
        if (p < BCAP) u2.bb.bndi[p] = q * 4 + t;
      }
    }
  }
  __syncthreads();
  int m = (hi > 0) ? ctl_m : 0;

  // ---- overflow fallback: exact 4-pass key radix (R3-proven; ~never) ----
  if (hi > 0 && m > BCAP) {
    if (tid == 0) { ctl_k = TOPK; ctl_pref = 0u; }
    __syncthreads();
    for (int shift = 24; shift >= 0; shift -= 8) {
      u1.r.hist[tid] = 0u;
      __syncthreads();
      unsigned pref = ctl_pref;
      for (int q = tid; q < NQ; q += 256) {
        float4 k4 = sc4[q];
        unsigned kb[4] = {__float_as_uint(k4.x), __float_as_uint(k4.y),
                          __float_as_uint(k4.z), __float_as_uint(k4.w)};
#pragma unroll
        for (int t = 0; t < 4; ++t) {
          unsigned key = kb[t];
          if (key == 0u) continue;
          bool match = (shift == 24) || ((key >> (shift + 8)) == (pref >> (shift + 8)));
          if (match) atomicAdd(&u1.r.hist[(key >> shift) & 255u], 1u);
        }
      }
      __syncthreads();
      if (tid == 0) {
        int k = ctl_k;
        unsigned cum = 0;
        int d = 255;
        for (; d > 0; --d) {
          unsigned h = u1.r.hist[d];
          if (cum + h >= (unsigned)k) break;
          cum += h;
        }
        ctl_k = k - (int)cum;
        ctl_pref = pref | ((unsigned)d << shift);
      }
      __syncthreads();
    }
    unsigned Tf = ctl_pref;
    kneed = ctl_k;
    n1 = TOPK - kneed;
    if (tid == 0) { ctl_cnt = 0; ctl_m = 0; }
    __syncthreads();
    for (int q = tid; q < NQ; q += 256) {
      float4 k4 = sc4[q];
      unsigned kb[4] = {__float_as_uint(k4.x), __float_as_uint(k4.y),
                        __float_as_uint(k4.z), __float_as_uint(k4.w)};
#pragma unroll
      for (int t = 0; t < 4; ++t) {
        unsigned key = kb[t];
        if (key > Tf) {
          int p = atomicAdd(&ctl_cnt, 1);
          if (p < 256) isel[p] = q * 4 + t;
        } else if (key == Tf) {
          int p = atomicAdd(&ctl_m, 1);
          if (p < BCAP) u2.bb.bndi[p] = q * 4 + t;
        }
      }
    }
    __syncthreads();
    m = ctl_m;
    if (m > BCAP) m = BCAP;
  }

  // ---- boundary: exact f64 (score desc, index asc) ranking ----
  if (hi > 0) {
    for (int q = tid; q < m; q += 256)
      u2.bb.bnds[q] = exact_score_cf(conf, b, u2.bb.bndi[q], c);
    __syncthreads();
    for (int q = tid; q < m; q += 256) {
      double sq = u2.bb.bnds[q];
      int iq = u2.bb.bndi[q];
      int rank = 0;
      for (int r = 0; r < m; ++r)
        if (entBefore(u2.bb.bnds[r], u2.bb.bndi[r], sq, iq)) ++rank;
      if (rank < kneed) isel[n1 + rank] = iq;
    }
  } else {
    // sparse: zero-score dummies (keep=false downstream -> zero rows)
    for (int j = n1 + tid; j < TOPK; j += 256) isel[j] = j - n1;
  }
  __syncthreads();
  int zf = (hi > 0) ? TOPK : n1;

  // ---- exact f64 scores + sort sentinels ----
  if (tid < TOPK) {
    ssel[tid] = (tid < zf) ? exact_score_cf(conf, b, isel[tid], c) : 0.0;
  } else {
    ssel[tid] = -1.0;
    isel[tid] = 0x7fffffff;
  }

  // ---- bitonic sort 256: (score desc, index asc) ----
  for (int kk = 2; kk <= 256; kk <<= 1) {
    for (int j = kk >> 1; j > 0; j >>= 1) {
      __syncthreads();
      int ixj = tid ^ j;
      if (ixj > tid) {
        double s1 = ssel[tid], s2 = ssel[ixj];
        int i1 = isel[tid], i2 = isel[ixj];
        bool up = ((tid & kk) == 0);
        bool sw = up ? entBefore(s2, i2, s1, i1) : entBefore(s1, i1, s2, i2);
        if (sw) {
          ssel[tid] = s2; ssel[ixj] = s1;
          isel[tid] = i2; isel[ixj] = i1;
        }
      }
    }
  }
  __syncthreads();

  // ---- decode in f64; keep own box in registers; f32 shadows to LDS ----
  double dx1 = 0, dy1 = 0, dx2 = 0, dy2 = 0, dar = 0;
  float fx1 = 0, fy1 = 0, fx2 = 0, fy2 = 0, far = 0;
  if (tid < TOPK) {
    int ai = isel[tid];
    const float* lp = loc + ((size_t)b * NA + ai) * 4;
    const float* ap = anchors + (size_t)ai * 4;
    double l0 = (double)lp[0], l1 = (double)lp[1];
    double l2 = (double)lp[2], l3 = (double)lp[3];
    double a0 = (double)ap[0], a1 = (double)ap[1];
    double a2 = (double)ap[2], a3 = (double)ap[3];
    double cx = a0 + (l0 * 0.1) * a2;
    double cy = a1 + (l1 * 0.1) * a3;
    double w = a2 * exp(l2 * 0.2);
    double h = a3 * exp(l3 * 0.2);
    dx1 = cx - 0.5 * w; dy1 = cy - 0.5 * h;
    dx2 = cx + 0.5 * w; dy2 = cy + 0.5 * h;
    dar = (dx2 - dx1) * (dy2 - dy1);
    u1.dbox[tid][0] = dx1; u1.dbox[tid][1] = dy1;
    u1.dbox[tid][2] = dx2; u1.dbox[tid][3] = dy2;
    fx1 = (float)dx1; fy1 = (float)dy1; fx2 = (float)dx2; fy2 = (float)dy2;
    far = (float)dar;
    fbox[tid] = make_float4(fx1, fy1, fx2, fy2);
    farea[tid] = far;
  }
  __syncthreads();

  // ---- suppression bits, uniform-j broadcast (conflict-free LDS reads) ----
  // f32 fast path; f64 recheck only in the guard band |iou-0.045|<~0.005.
  if (tid < TOPK) {
    unsigned bits = 0u;
    int w = 0;
    for (int j = 0; j < TOPK; ++j) {
      float4 fb = fbox[j];                    // broadcast b128
      float lx = fmaxf(fx1, fb.x), ly = fmaxf(fy1, fb.y);
      float rx = fminf(fx2, fb.z), ry = fminf(fy2, fb.w);
      float iw = fmaxf(rx - lx, 0.0f), ih = fmaxf(ry - ly, 0.0f);
      float inter = iw * ih;
      float io = inter / (far + farea[j] - inter + 1e-12f);
      bool sup;
      if (io > 0.040f && io < 0.050f) {       // rare; j uniform -> broadcast
        double jx1 = u1.dbox[j][0], jy1 = u1.dbox[j][1];
        double jx2 = u1.dbox[j][2], jy2 = u1.dbox[j][3];
        double dlx = fmax(dx1, jx1), dly = fmax(dy1, jy1);
        double drx = fmin(dx2, jx2), dry = fmin(dy2, jy2);
        double diw = drx - dlx; if (diw < 0.0) diw = 0.0;
        double dih = dry - dly; if (dih < 0.0) dih = 0.0;
        double dint = diw * dih;
        double jar = (jx2 - jx1) * (jy2 - jy1);
        sup = dint > NMS_T * (dar + jar - dint + 1e-12);
      } else {
        sup = io > 0.045f;
      }
      if (j > tid && sup) bits |= 1u << (j & 31);
      if ((j & 31) == 31) { u2.supp[tid][w] = bits; bits = 0u; ++w; }
    }
    u2.supp[tid][6] = bits;   // j = 192..199
    u2.supp[tid][7] = 0u;     // padding read by NMS (base=1, q=3)
  }
  __syncthreads();

  // ---- greedy NMS on wave 0: keep bits in registers, next-row prefetch ----
  if (tid < 64) {
    int l = tid;
    unsigned kr = 0u;
#pragma unroll
    for (int q = 0; q < 4; ++q) {
      int j = l + 64 * q;
      if (j < TOPK && ssel[j] > CONF_T) kr |= 1u << q;
    }
    int base = l >> 5;  // 0 or 1
    unsigned r0 = u2.supp[0][base], r1 = u2.supp[0][base + 2];
    unsigned r2 = u2.supp[0][base + 4], r3 = u2.supp[0][base + 6];
    for (int i = 0; i < TOPK; ++i) {
      int ip = (i + 1 < TOPK) ? i + 1 : i;
      unsigned p0 = u2.supp[ip][base], p1 = u2.supp[ip][base + 2];
      unsigned p2 = u2.supp[ip][base + 4], p3 = u2.supp[ip][base + 6];
      unsigned krow = (unsigned)__shfl((int)kr, i & 63);
      if ((krow >> (i >> 6)) & 1u) {
        unsigned bm = 1u << (l & 31);
        if (r0 & bm) kr &= ~1u;
        if (r1 & bm) kr &= ~2u;
        if (r2 & bm) kr &= ~4u;
        if (r3 & bm) kr &= ~8u;
      }
      r0 = p0; r1 = p1; r2 = p2; r3 = p3;
    }
#pragma unroll
    for (int q = 0; q < 4; ++q) {
      unsigned long long bal = __ballot((int)((kr >> q) & 1u));
      if (l == 0) {
        keepw[2 * q] = (unsigned)bal;
        if (2 * q + 1 < 7) keepw[2 * q + 1] = (unsigned)(bal >> 32);
      }
    }
  }
  __syncthreads();

  // ---- pack kept rows to the front, zero-fill the rest ----
  int nk = 0;
#pragma unroll
  for (int w = 0; w < 7; ++w) nk += __popc(keepw[w]);
  if (tid < TOPK) {
    int j = tid;
    bool kept = (keepw[j >> 5] >> (j & 31)) & 1u;
    if (kept) {
      int pos = 0;
      for (int w = 0; w < (j >> 5); ++w) pos += __popc(keepw[w]);
      pos += __popc(keepw[j >> 5] & ((1u << (j & 31)) - 1u));
      float* o = outbase + (size_t)pos * 5;
      o[0] = (float)ssel[j];
      o[1] = (float)u1.dbox[j][0];
      o[2] = (float)u1.dbox[j][1];
      o[3] = (float)u1.dbox[j][2];
      o[4] = (float)u1.dbox[j][3];
    }
    if (j >= nk) {
      float* o = outbase + (size_t)j * 5;
      o[0] = 0.0f; o[1] = 0.0f; o[2] = 0.0f; o[3] = 0.0f; o[4] = 0.0f;
    }
  }
}

// ===========================================================================
// Tiny-workspace fallback (R2-proven, self-contained) — only if ws too small
// ===========================================================================
__global__ __launch_bounds__(256) void k_main_nf(const float* __restrict__ loc,
                                                 const float* __restrict__ conf,
                                                 const float* __restrict__ anchors,
                                                 float* __restrict__ out) {
  int bc = blockIdx.x;
  int b = bc / NC;
  int c = bc % NC;
  int tid = threadIdx.x;
  float* outbase = out + (size_t)bc * TOPK * 5;
  if (c == 0) {
    for (int k = tid; k < TOPK * 5; k += 256) outbase[k] = 0.0f;
    return;
  }
  union U {
    float sf[NA];
    struct { double box[TOPK][4]; double area[TOPK]; } p2;
  };
  __shared__ U u;
  __shared__ double ssel[256];
  __shared__ int isel[256];
  __shared__ unsigned hist[256];
  __shared__ double bnds[256];
  __shared__ int bndi[256];
  __shared__ int keepL[256];
  __shared__ unsigned long long wmask[4];
  __shared__ int ctl_k, ctl_cnt, ctl_m;
  __shared__ unsigned ctl_pref;

  for (int i = tid; i < NA; i += 256)
    u.sf[i] = (float)exact_score_cf(conf, b, i, c);
  if (tid == 0) { ctl_k = TOPK; ctl_pref = 0u; }
  __syncthreads();
  for (int shift = 24; shift >= 0; shift -= 8) {
    hist[tid] = 0u;
    __syncthreads();
    unsigned pref = ctl_pref;
    for (int i = tid; i < NA; i += 256) {
      unsigned key = __float_as_uint(u.sf[i]);
      bool match = (shift == 24) || ((key >> (shift + 8)) == (pref >> (shift + 8)));
      if (match) atomicAdd(&hist[(key >> shift) & 255u], 1u);
    }
    __syncthreads();
    if (tid == 0) {
      int k = ctl_k;
      unsigned cum = 0;
      int d = 255;
      for (; d > 0; --d) {
        unsigned h = hist[d];
        if (cum + h >= (unsigned)k) break;
        cum += h;
      }
      ctl_k = k - (int)cum;
      ctl_pref = pref | ((unsigned)d << shift);
    }
    __syncthreads();
  }
  unsigned Tf = ctl_pref;
  int kneed = ctl_k;
  int n1 = TOPK - kneed;
  if (tid == 0) { ctl_cnt = 0; ctl_m = 0; }
  __syncthreads();
  for (int i = tid; i < NA; i += 256) {
    unsigned key = __float_as_uint(u.sf[i]);
    if (key > Tf) {
      int p = atomicAdd(&ctl_cnt, 1);
      if (p < 256) isel[p] = i;
    } else if (key == Tf && Tf != 0u) {
      int q = atomicAdd(&ctl_m, 1);
      if (q < 256) bndi[q] = i;
    }
  }
  __syncthreads();
  int zf;
  if (Tf == 0u) {
    zf = n1;
    for (int j = n1 + tid; j < TOPK; j += 256) isel[j] = j - n1;
  } else {
    zf = TOPK;
    int m = ctl_m;
    if (m > 256) m = 256;
    if (tid < m) bnds[tid] = exact_score_cf(conf, b, bndi[tid], c);
    __syncthreads();
    if (tid < m) {
      double sq = bnds[tid];
      int iq = bndi[tid];
      int rank = 0;
      for (int r = 0; r < m; ++r)
        if (entBefore(bnds[r], bndi[r], sq, iq)) ++rank;
      if (rank < kneed) isel[n1 + rank] = iq;
    }
  }
  __syncthreads();
  if (tid < TOPK) {
    ssel[tid] = (tid < zf) ? exact_score_cf(conf, b, isel[tid], c) : 0.0;
  } else {
    ssel[tid] = -1.0;
    isel[tid] = 0x7fffffff;
  }
  for (int kk = 2; kk <= 256; kk <<= 1) {
    for (int j = kk >> 1; j > 0; j >>= 1) {
      __syncthreads();
      int ixj = tid ^ j;
      if (ixj > tid) {
        double s1 = ssel[tid], s2 = ssel[ixj];
        int i1 = isel[tid], i2 = isel[ixj];
        bool up = ((tid & kk) == 0);
        bool sw = up ? entBefore(s2, i2, s1, i1) : entBefore(s1, i1, s2, i2);
        if (sw) {
          ssel[tid] = s2; ssel[ixj] = s1;
          isel[tid] = i2; isel[ixj] = i1;
        }
      }
    }
  }
  __syncthreads();
  if (tid < TOPK) {
    int ai = isel[tid];
    const float* lp = loc + ((size_t)b * NA + ai) * 4;
    const float* ap = anchors + (size_t)ai * 4;
    double l0 = (double)lp[0], l1 = (double)lp[1];
    double l2 = (double)lp[2], l3 = (double)lp[3];
    double a0 = (double)ap[0], a1 = (double)ap[1];
    double a2 = (double)ap[2], a3 = (double)ap[3];
    double cx = a0 + (l0 * 0.1) * a2;
    double cy = a1 + (l1 * 0.1) * a3;
    double w = a2 * exp(l2 * 0.2);
    double h = a3 * exp(l3 * 0.2);
    double x1 = cx - 0.5 * w, y1 = cy - 0.5 * h;
    double x2 = cx + 0.5 * w, y2 = cy + 0.5 * h;
    u.p2.box[tid][0] = x1; u.p2.box[tid][1] = y1;
    u.p2.box[tid][2] = x2; u.p2.box[tid][3] = y2;
    u.p2.area[tid] = (x2 - x1) * (y2 - y1);
  }
  __syncthreads();
  double mx1 = 0, my1 = 0, mx2 = 0, my2 = 0, mar = 0;
  if (tid < TOPK) {
    mx1 = u.p2.box[tid][0]; my1 = u.p2.box[tid][1];
    mx2 = u.p2.box[tid][2]; my2 = u.p2.box[tid][3];
    mar = u.p2.area[tid];
  }
  keepL[tid] = (tid < TOPK) && (ssel[tid] > CONF_T);
  __syncthreads();
  for (int i = 0; i < TOPK; ++i) {
    int ki = keepL[i];
    if (ki && tid > i && tid < TOPK && keepL[tid]) {
      double lx = fmax(u.p2.box[i][0], mx1);
      double ly = fmax(u.p2.box[i][1], my1);
      double rx = fmin(u.p2.box[i][2], mx2);
      double ry = fmin(u.p2.box[i][3], my2);
      double iw = rx - lx; if (iw < 0.0) iw = 0.0;
      double ih = ry - ly; if (ih < 0.0) ih = 0.0;
      double inter = iw * ih;
      double iou = inter / (u.p2.area[i] + mar - inter + 1e-12);
      if (iou > NMS_T) keepL[tid] = 0;
    }
    __syncthreads();
  }
  bool kj = (tid < TOPK) && (keepL[tid] != 0);
  unsigned long long bal = __ballot((int)kj);
  int wave = tid >> 6, lane = tid & 63;
  if (lane == 0) wmask[wave] = bal;
  __syncthreads();
  int nk = 0;
#pragma unroll
  for (int w = 0; w < 4; ++w) nk += __popcll(wmask[w]);
  if (kj) {
    int pos = 0;
    for (int w = 0; w < wave; ++w) pos += __popcll(wmask[w]);
    pos += __popcll(bal & ((1ull << lane) - 1ull));
    float* o = outbase + (size_t)pos * 5;
    o[0] = (float)ssel[tid];
    o[1] = (float)u.p2.box[tid][0];
    o[2] = (float)u.p2.box[tid][1];
    o[3] = (float)u.p2.box[tid][2];
    o[4] = (float)u.p2.box[tid][3];
  }
  if (tid < TOPK && tid >= nk) {
    float* o = outbase + (size_t)tid * 5;
    o[0] = 0.0f; o[1] = 0.0f; o[2] = 0.0f; o[3] = 0.0f; o[4] = 0.0f;
  }
}

// ---------------------------------------------------------------------------
extern "C" void kernel_launch(void* const* d_in, const int* in_sizes, int n_in,
                              void* d_out, int out_size, void* d_ws, size_t ws_size,
                              hipStream_t stream) {
  const float* loc = (const float*)d_in[0];
  const float* conf = (const float*)d_in[1];
  const float* anchors = (const float*)d_in[2];
  float* out = (float*)d_out;

  const size_t WS_NEED = (size_t)NB * (NC - 1) * NA * sizeof(float);
  if (ws_size >= WS_NEED) {
    float* scores = (float*)d_ws;
    k_prep<<<(NB * NA) / 256, 256, 0, stream>>>(conf, scores);
    k_fast<<<NB * NC, 256, 0, stream>>>(loc, conf, anchors, scores, out);
  } else {
    k_main_nf<<<NB * NC, 256, 0, stream>>>(loc, conf, anchors, out);
  }
}

// Round 6
// 347.841 us; speedup vs baseline: 1.2686x; 1.2686x over previous
//
#include <hip/hip_runtime.h>
#include <math.h>

#pragma clang fp contract(off)

#define NB 128
#define NA 8732
#define NC 21
#define TOPK 200
#define BCAP 512
#define CONF_T 0.01
#define NMS_T 0.045
#define NQ (NA / 4)   // 2183 float4 per class row
#define HSIZE 1024    // coarse buckets over f32 key bits [30:16]

// ---------------------------------------------------------------------------
// exact f64 masked softmax score, self-contained from conf (op order == np ref)
// ---------------------------------------------------------------------------
__device__ __forceinline__ double exact_score_cf(const float* __restrict__ conf,
                                                 int b, int i, int c) {
  const float* row = conf + ((size_t)b * NA + i) * NC;
  float r[NC];
#pragma unroll
  for (int k = 0; k < NC; ++k) r[k] = row[k];
  float mx = r[0];
#pragma unroll
  for (int k = 1; k < NC; ++k) mx = fmaxf(mx, r[k]);
  double d = 0.0;
#pragma unroll
  for (int k = 0; k < NC; ++k) d += exp((double)r[k] - (double)mx);
  double s = exp((double)r[c] - (double)mx) / d;
  return (s > CONF_T) ? s : 0.0;
}

// f64 decode of one box (op order == np ref)
__device__ __forceinline__ void decode64(const float* __restrict__ loc,
                                         const float* __restrict__ anchors,
                                         int b, int ai, double* o) {
  const float* lp = loc + ((size_t)b * NA + ai) * 4;
  const float* ap = anchors + (size_t)ai * 4;
  double l0 = (double)lp[0], l1 = (double)lp[1];
  double l2 = (double)lp[2], l3 = (double)lp[3];
  double a0 = (double)ap[0], a1 = (double)ap[1];
  double a2 = (double)ap[2], a3 = (double)ap[3];
  double cx = a0 + (l0 * 0.1) * a2;
  double cy = a1 + (l1 * 0.1) * a3;
  double w = a2 * exp(l2 * 0.2);
  double h = a3 * exp(l3 * 0.2);
  o[0] = cx - 0.5 * w; o[1] = cy - 0.5 * h;
  o[2] = cx + 0.5 * w; o[3] = cy + 0.5 * h;
}

__device__ __forceinline__ bool entBefore(double sa, int ia, double sb, int ib) {
  return (sa > sb) || (sa == sb && ia < ib);
}

// coarse bucket of an f32 score key; -1 = zero key. Monotone in key value.
// Nonzero keys live in (0.0099, 1]: x in [~35, 898] -- clamps never active.
__device__ __forceinline__ int kbucket(unsigned key) {
  if (key == 0u) return -1;
  int x = (int)(key >> 16) - 0x3C00 + 1;
  if (x < 1) x = 1;
  if (x > HSIZE - 1) x = HSIZE - 1;
  return x;
}

// ---------------------------------------------------------------------------
// k_prep: f32 softmax keys (HW expf). Key rel err ~2e-6 << bucket width 0.78%;
// the {D-1,D,D+1} exact-f64 boundary resolution in k_fast absorbs all key
// error. Mask relaxed to 0.0099 so f32 error cannot wrongly zero a key near
// 0.01 (sub-threshold selections resolve to exact 0 downstream -> zero rows).
// ---------------------------------------------------------------------------
__global__ __launch_bounds__(256) void k_prep(const float* __restrict__ conf,
                                              float* __restrict__ scores) {
  __shared__ float rows[256 * NC];
  int base = blockIdx.x * 256;                  // NB*NA == 4366*256 exactly
  const float4* src = (const float4*)(conf + (size_t)base * NC);
  float4* dst = (float4*)rows;
  for (int t = threadIdx.x; t < (256 * NC) / 4; t += 256) dst[t] = src[t];
  __syncthreads();
  int g = base + threadIdx.x;
  const float* row = rows + threadIdx.x * NC;
  float v[NC];
#pragma unroll
  for (int k = 0; k < NC; ++k) v[k] = row[k];
  float mx = v[0];
#pragma unroll
  for (int k = 1; k < NC; ++k) mx = fmaxf(mx, v[k]);
  float e[NC], s = 0.0f;
#pragma unroll
  for (int k = 0; k < NC; ++k) {
    e[k] = expf(v[k] - mx);
    s += e[k];
  }
  float inv = 1.0f / s;
  int b = g / NA, i = g - b * NA;
#pragma unroll
  for (int cc = 1; cc < NC; ++cc) {
    float sc = e[cc] * inv;
    scores[(size_t)(b * (NC - 1) + (cc - 1)) * NA + i] = (sc > 0.0099f) ? sc : 0.0f;
  }
}

// ---------------------------------------------------------------------------
// k_fast: one 256-thread block per (b,c), XCD-swizzled, 8 blocks/CU.
// ---------------------------------------------------------------------------
__global__ __launch_bounds__(256, 8) void k_fast(const float* __restrict__ loc,
                                                 const float* __restrict__ conf,
                                                 const float* __restrict__ anchors,
                                                 const float* __restrict__ scores,
                                                 float* __restrict__ out) {
  int id = blockIdx.x;
  int xcd = id & 7, slot = id >> 3;     // same-b classes share an XCD
  int c = slot % NC;
  int b = (slot / NC) * 8 + xcd;
  int tid = threadIdx.x;
  float* outbase = out + ((size_t)(b * NC + c)) * TOPK * 5;

  if (c == 0) {
    for (int k = tid; k < TOPK * 5; k += 256) outbase[k] = 0.0f;
    return;
  }

  __shared__ unsigned hist[HSIZE];    // 4096 B (fallback radix reuses [0:256))
  __shared__ unsigned chunk[256];     // 1024 B
  __shared__ unsigned chunk2[32];     // 128 B
  union U2 {  // boundary phase vs suppression phase (disjoint in time)
    struct { double bnds[BCAP]; int bndi[BCAP]; } bb;  // 6144 B
    unsigned supp[TOPK][9];  // stride 9 (coprime 32): conflict-free writes
  };
  __shared__ U2 u2;
  __shared__ float4 fbox[TOPK];   // f32 shadow boxes (b128 broadcast reads)
  __shared__ float farea[TOPK];
  __shared__ double ssel[256];
  __shared__ int isel[256];
  __shared__ unsigned keepw[7];
  __shared__ int ctl_cnt, ctl_m, ctl_n1, ctl_kneed, ctl_lo, ctl_hi, ctl_k;
  __shared__ unsigned ctl_pref;

  const float4* sc4 =
      (const float4*)(scores + (size_t)(b * (NC - 1) + (c - 1)) * NA);

  // ---- single-pass coarse histogram (zeros skipped) ----
  for (int t = tid; t < HSIZE; t += 256) hist[t] = 0u;
  if (tid == 0) { ctl_cnt = 0; ctl_m = 0; }
  __syncthreads();
  for (int q = tid; q < NQ; q += 256) {
    float4 k4 = sc4[q];
    unsigned kb[4] = {__float_as_uint(k4.x), __float_as_uint(k4.y),
                      __float_as_uint(k4.z), __float_as_uint(k4.w)};
#pragma unroll
    for (int t = 0; t < 4; ++t) {
      int idx = kbucket(kb[t]);
      if (idx >= 0) atomicAdd(&hist[idx], 1u);
    }
  }
  __syncthreads();

  // ---- find boundary bucket D via two-level suffix scan ----
  {
    unsigned csum = 0;
#pragma unroll
    for (int j = 0; j < 4; ++j) csum += hist[tid * 4 + j];
    chunk[tid] = csum;
  }
  __syncthreads();
  if (tid < 32) {
    unsigned s = 0;
#pragma unroll
    for (int j = 0; j < 8; ++j) s += chunk[tid * 8 + j];
    chunk2[tid] = s;
  }
  __syncthreads();
  if (tid == 0) {
    unsigned cum = 0;
    int t2 = -1;
    for (int t = 31; t >= 0; --t) {
      unsigned h = chunk2[t];
      if (cum + h >= (unsigned)TOPK) { t2 = t; break; }
      cum += h;
    }
    if (t2 < 0) {  // sparse: fewer than 200 nonzero keys
      ctl_lo = 1; ctl_hi = 0; ctl_n1 = (int)cum; ctl_kneed = TOPK - (int)cum;
    } else {
      int tc = t2 * 8;
      for (int t = t2 * 8 + 7; t >= t2 * 8; --t) {
        unsigned h = chunk[t];
        if (cum + h >= (unsigned)TOPK) { tc = t; break; }
        cum += h;
      }
      int D = tc * 4;
      for (int j = tc * 4 + 3; j >= tc * 4; --j) {
        unsigned h = hist[j];
        if (cum + h >= (unsigned)TOPK) { D = j; break; }
        cum += h;
      }
      int hi = (D + 1 < HSIZE) ? D + 1 : D;
      int lo = (D - 1 >= 1) ? D - 1 : D;
      unsigned hup = (hi > D) ? hist[hi] : 0u;
      ctl_lo = lo; ctl_hi = hi;
      ctl_n1 = (int)(cum - hup);        // count(buckets > hi)
      ctl_kneed = TOPK - ctl_n1;
    }
  }
  __syncthreads();
  int lo = ctl_lo, hi = ctl_hi, n1 = ctl_n1, kneed = ctl_kneed;

  // ---- collect: certain (bucket > hi) and boundary (lo..hi) ----
  for (int q = tid; q < NQ; q += 256) {
    float4 k4 = sc4[q];
    unsigned kb[4] = {__float_as_uint(k4.x), __float_as_uint(k4.y),
                      __float_as_uint(k4.z), __float_as_uint(k4.w)};
#pragma unroll
    for (int t = 0; t < 4; ++t) {
      int idx = kbucket(kb[t]);
      if (idx < 0) continue;
      if (idx > hi) {
        int p = atomicAdd(&ctl_cnt, 1);
        if (p < 256) isel[p] = q * 4 + t;      // exactly n1 <= 199 entries
      } else if (idx >= lo) {
        int p = atomicAdd(&ctl_m, 1);
        if (p < BCAP) u2.bb.bndi[p] = q * 4 + t;
      }
    }
  }
  __syncthreads();
  int m = (hi > 0) ? ctl_m : 0;

  // ---- overflow fallback: exact 4-pass key radix (R3-proven; ~never) ----
  if (hi > 0 && m > BCAP) {
    if (tid == 0) { ctl_k = TOPK; ctl_pref = 0u; }
    __syncthreads();
    for (int shift = 24; shift >= 0; shift -= 8) {
      hist[tid] = 0u;
      __syncthreads();
      unsigned pref = ctl_pref;
      for (int q = tid; q < NQ; q += 256) {
        float4 k4 = sc4[q];
        unsigned kb[4] = {__float_as_uint(k4.x), __float_as_uint(k4.y),
                          __float_as_uint(k4.z), __float_as_uint(k4.w)};
#pragma unroll
        for (int t = 0; t < 4; ++t) {
          unsigned key = kb[t];
          if (key == 0u) continue;
          bool match = (shift == 24) || ((key >> (shift + 8)) == (pref >> (shift + 8)));
          if (match) atomicAdd(&hist[(key >> shift) & 255u], 1u);
        }
      }
      __syncthreads();
      if (tid == 0) {
        int k = ctl_k;
        unsigned cum = 0;
        int d = 255;
        for (; d > 0; --d) {
          unsigned h = hist[d];
          if (cum + h >= (unsigned)k) break;
          cum += h;
        }
        ctl_k = k - (int)cum;
        ctl_pref = pref | ((unsigned)d << shift);
      }
      __syncthreads();
    }
    unsigned Tf = ctl_pref;
    kneed = ctl_k;
    n1 = TOPK - kneed;
    if (tid == 0) { ctl_cnt = 0; ctl_m = 0; }
    __syncthreads();
    for (int q = tid; q < NQ; q += 256) {
      float4 k4 = sc4[q];
      unsigned kb[4] = {__float_as_uint(k4.x), __float_as_uint(k4.y),
                        __float_as_uint(k4.z), __float_as_uint(k4.w)};
#pragma unroll
      for (int t = 0; t < 4; ++t) {
        unsigned key = kb[t];
        if (key > Tf) {
          int p = atomicAdd(&ctl_cnt, 1);
          if (p < 256) isel[p] = q * 4 + t;
        } else if (key == Tf) {
          int p = atomicAdd(&ctl_m, 1);
          if (p < BCAP) u2.bb.bndi[p] = q * 4 + t;
        }
      }
    }
    __syncthreads();
    m = ctl_m;
    if (m > BCAP) m = BCAP;
  }

  // ---- boundary: exact f64 ranking; winners carry their exact score ----
  if (hi > 0) {
    for (int q = tid; q < m; q += 256)
      u2.bb.bnds[q] = exact_score_cf(conf, b, u2.bb.bndi[q], c);
    __syncthreads();
    for (int q = tid; q < m; q += 256) {
      double sq = u2.bb.bnds[q];
      int iq = u2.bb.bndi[q];
      int rank = 0;
      for (int r = 0; r < m; ++r)
        if (entBefore(u2.bb.bnds[r], u2.bb.bndi[r], sq, iq)) ++rank;
      if (rank < kneed) { isel[n1 + rank] = iq; ssel[n1 + rank] = sq; }
    }
  } else {
    // sparse: zero-score dummies (keep=false downstream -> zero rows)
    for (int j = n1 + tid; j < TOPK; j += 256) {
      isel[j] = j - n1;
      ssel[j] = 0.0;
    }
  }
  __syncthreads();

  // ---- exact f64 scores for "certain" entries + sort sentinels ----
  if (tid < TOPK) {
    if (tid < n1) ssel[tid] = exact_score_cf(conf, b, isel[tid], c);
    // tid in [n1,TOPK): already written by boundary/sparse phase
  } else {
    ssel[tid] = -1.0;
    isel[tid] = 0x7fffffff;
  }

  // ---- bitonic sort 256: (score desc, index asc) ----
  for (int kk = 2; kk <= 256; kk <<= 1) {
    for (int j = kk >> 1; j > 0; j >>= 1) {
      __syncthreads();
      int ixj = tid ^ j;
      if (ixj > tid) {
        double s1 = ssel[tid], s2 = ssel[ixj];
        int i1 = isel[tid], i2 = isel[ixj];
        bool up = ((tid & kk) == 0);
        bool sw = up ? entBefore(s2, i2, s1, i1) : entBefore(s1, i1, s2, i2);
        if (sw) {
          ssel[tid] = s2; ssel[ixj] = s1;
          isel[tid] = i2; isel[ixj] = i1;
        }
      }
    }
  }
  __syncthreads();

  // ---- decode own box in f64 (registers); f32 shadow to LDS ----
  double dx1 = 0, dy1 = 0, dx2 = 0, dy2 = 0, dar = 0;
  float fx1 = 0, fy1 = 0, fx2 = 0, fy2 = 0, far = 0;
  if (tid < TOPK) {
    double bx[4];
    decode64(loc, anchors, b, isel[tid], bx);
    dx1 = bx[0]; dy1 = bx[1]; dx2 = bx[2]; dy2 = bx[3];
    dar = (dx2 - dx1) * (dy2 - dy1);
    fx1 = (float)dx1; fy1 = (float)dy1; fx2 = (float)dx2; fy2 = (float)dy2;
    far = (float)dar;
    fbox[tid] = make_float4(fx1, fy1, fx2, fy2);
    farea[tid] = far;
  }
  __syncthreads();

  // ---- suppression bits: upper triangle, mult-compare, tight f64 guard ----
  if (tid < TOPK) {
    int wstart = tid >> 5;
    for (int w = 0; w < wstart; ++w) u2.supp[tid][w] = 0u;
    for (int w = wstart; w < 7; ++w) {
      int j0 = w * 32;
      int j1 = j0 + 32;
      if (j1 > TOPK) j1 = TOPK;
      int js = (j0 > tid + 1) ? j0 : tid + 1;
      unsigned bits = 0u;
      for (int j = js; j < j1; ++j) {
        float4 fb = fbox[j];                    // broadcast b128
        float lx = fmaxf(fx1, fb.x), ly = fmaxf(fy1, fb.y);
        float rx = fminf(fx2, fb.z), ry = fminf(fy2, fb.w);
        float iw = fmaxf(rx - lx, 0.0f), ih = fmaxf(ry - ly, 0.0f);
        float inter = iw * ih;
        float uni = far + farea[j] - inter + 1e-12f;
        float diff = inter - 0.045f * uni;      // sign(diff) == sign(io-T)
        bool sup;
        if (fabsf(diff) < 3e-4f * uni) {        // |io-T| < 3e-4: decide in f64
          double jb[4];
          decode64(loc, anchors, b, isel[j], jb);
          double dlx = fmax(dx1, jb[0]), dly = fmax(dy1, jb[1]);
          double drx = fmin(dx2, jb[2]), dry = fmin(dy2, jb[3]);
          double diw = drx - dlx; if (diw < 0.0) diw = 0.0;
          double dih = dry - dly; if (dih < 0.0) dih = 0.0;
          double dint = diw * dih;
          double jar = (jb[2] - jb[0]) * (jb[3] - jb[1]);
          sup = dint > NMS_T * (dar + jar - dint + 1e-12);
        } else {
          sup = diff > 0.0f;
        }
        if (sup) bits |= 1u << (j & 31);
      }
      u2.supp[tid][w] = bits;
    }
    u2.supp[tid][7] = 0u;   // pad word read by NMS (base=1, q=3)
  }
  __syncthreads();

  // ---- greedy NMS on wave 0: keep bits in registers, next-row prefetch ----
  if (tid < 64) {
    int l = tid;
    unsigned kr = 0u;
#pragma unroll
    for (int q = 0; q < 4; ++q) {
      int j = l + 64 * q;
      if (j < TOPK && ssel[j] > CONF_T) kr |= 1u << q;
    }
    int base = l >> 5;  // 0 or 1
    unsigned r0 = u2.supp[0][base], r1 = u2.supp[0][base + 2];
    unsigned r2 = u2.supp[0][base + 4], r3 = u2.supp[0][base + 6];
    for (int i = 0; i < TOPK; ++i) {
      int ip = (i + 1 < TOPK) ? i + 1 : i;
      unsigned p0 = u2.supp[ip][base], p1 = u2.supp[ip][base + 2];
      unsigned p2 = u2.supp[ip][base + 4], p3 = u2.supp[ip][base + 6];
      unsigned krow = (unsigned)__shfl((int)kr, i & 63);
      if ((krow >> (i >> 6)) & 1u) {
        unsigned bm = 1u << (l & 31);
        if (r0 & bm) kr &= ~1u;
        if (r1 & bm) kr &= ~2u;
        if (r2 & bm) kr &= ~4u;
        if (r3 & bm) kr &= ~8u;
      }
      r0 = p0; r1 = p1; r2 = p2; r3 = p3;
    }
#pragma unroll
    for (int q = 0; q < 4; ++q) {
      unsigned long long bal = __ballot((int)((kr >> q) & 1u));
      if (l == 0) {
        keepw[2 * q] = (unsigned)bal;
        if (2 * q + 1 < 7) keepw[2 * q + 1] = (unsigned)(bal >> 32);
      }
    }
  }
  __syncthreads();

  // ---- pack kept rows to the front, zero-fill the rest ----
  int nk = 0;
#pragma unroll
  for (int w = 0; w < 7; ++w) nk += __popc(keepw[w]);
  if (tid < TOPK) {
    int j = tid;
    bool kept = (keepw[j >> 5] >> (j & 31)) & 1u;
    if (kept) {
      int pos = 0;
      for (int w = 0; w < (j >> 5); ++w) pos += __popc(keepw[w]);
      pos += __popc(keepw[j >> 5] & ((1u << (j & 31)) - 1u));
      float* o = outbase + (size_t)pos * 5;
      o[0] = (float)ssel[j];
      o[1] = (float)dx1;
      o[2] = (float)dy1;
      o[3] = (float)dx2;
      o[4] = (float)dy2;
    }
    if (j >= nk) {
      float* o = outbase + (size_t)j * 5;
      o[0] = 0.0f; o[1] = 0.0f; o[2] = 0.0f; o[3] = 0.0f; o[4] = 0.0f;
    }
  }
}

// ===========================================================================
// Tiny-workspace fallback (R2-proven, self-contained) — only if ws too small
// ===========================================================================
__global__ __launch_bounds__(256) void k_main_nf(const float* __restrict__ loc,
                                                 const float* __restrict__ conf,
                                                 const float* __restrict__ anchors,
                                                 float* __restrict__ out) {
  int bc = blockIdx.x;
  int b = bc / NC;
  int c = bc % NC;
  int tid = threadIdx.x;
  float* outbase = out + (size_t)bc * TOPK * 5;
  if (c == 0) {
    for (int k = tid; k < TOPK * 5; k += 256) outbase[k] = 0.0f;
    return;
  }
  union U {
    float sf[NA];
    struct { double box[TOPK][4]; double area[TOPK]; } p2;
  };
  __shared__ U u;
  __shared__ double ssel[256];
  __shared__ int isel[256];
  __shared__ unsigned hist[256];
  __shared__ double bnds[256];
  __shared__ int bndi[256];
  __shared__ int keepL[256];
  __shared__ unsigned long long wmask[4];
  __shared__ int ctl_k, ctl_cnt, ctl_m;
  __shared__ unsigned ctl_pref;

  for (int i = tid; i < NA; i += 256)
    u.sf[i] = (float)exact_score_cf(conf, b, i, c);
  if (tid == 0) { ctl_k = TOPK; ctl_pref = 0u; }
  __syncthreads();
  for (int shift = 24; shift >= 0; shift -= 8) {
    hist[tid] = 0u;
    __syncthreads();
    unsigned pref = ctl_pref;
    for (int i = tid; i < NA; i += 256) {
      unsigned key = __float_as_uint(u.sf[i]);
      bool match = (shift == 24) || ((key >> (shift + 8)) == (pref >> (shift + 8)));
      if (match) atomicAdd(&hist[(key >> shift) & 255u], 1u);
    }
    __syncthreads();
    if (tid == 0) {
      int k = ctl_k;
      unsigned cum = 0;
      int d = 255;
      for (; d > 0; --d) {
        unsigned h = hist[d];
        if (cum + h >= (unsigned)k) break;
        cum += h;
      }
      ctl_k = k - (int)cum;
      ctl_pref = pref | ((unsigned)d << shift);
    }
    __syncthreads();
  }
  unsigned Tf = ctl_pref;
  int kneed = ctl_k;
  int n1 = TOPK - kneed;
  if (tid == 0) { ctl_cnt = 0; ctl_m = 0; }
  __syncthreads();
  for (int i = tid; i < NA; i += 256) {
    unsigned key = __float_as_uint(u.sf[i]);
    if (key > Tf) {
      int p = atomicAdd(&ctl_cnt, 1);
      if (p < 256) isel[p] = i;
    } else if (key == Tf && Tf != 0u) {
      int q = atomicAdd(&ctl_m, 1);
      if (q < 256) bndi[q] = i;
    }
  }
  __syncthreads();
  int zf;
  if (Tf == 0u) {
    zf = n1;
    for (int j = n1 + tid; j < TOPK; j += 256) isel[j] = j - n1;
  } else {
    zf = TOPK;
    int m = ctl_m;
    if (m > 256) m = 256;
    if (tid < m) bnds[tid] = exact_score_cf(conf, b, bndi[tid], c);
    __syncthreads();
    if (tid < m) {
      double sq = bnds[tid];
      int iq = bndi[tid];
      int rank = 0;
      for (int r = 0; r < m; ++r)
        if (entBefore(bnds[r], bndi[r], sq, iq)) ++rank;
      if (rank < kneed) isel[n1 + rank] = iq;
    }
  }
  __syncthreads();
  if (tid < TOPK) {
    ssel[tid] = (tid < zf) ? exact_score_cf(conf, b, isel[tid], c) : 0.0;
  } else {
    ssel[tid] = -1.0;
    isel[tid] = 0x7fffffff;
  }
  for (int kk = 2; kk <= 256; kk <<= 1) {
    for (int j = kk >> 1; j > 0; j >>= 1) {
      __syncthreads();
      int ixj = tid ^ j;
      if (ixj > tid) {
        double s1 = ssel[tid], s2 = ssel[ixj];
        int i1 = isel[tid], i2 = isel[ixj];
        bool up = ((tid & kk) == 0);
        bool sw = up ? entBefore(s2, i2, s1, i1) : entBefore(s1, i1, s2, i2);
        if (sw) {
          ssel[tid] = s2; ssel[ixj] = s1;
          isel[tid] = i2; isel[ixj] = i1;
        }
      }
    }
  }
  __syncthreads();
  if (tid < TOPK) {
    double bx[4];
    decode64(loc, anchors, b, isel[tid], bx);
    u.p2.box[tid][0] = bx[0]; u.p2.box[tid][1] = bx[1];
    u.p2.box[tid][2] = bx[2]; u.p2.box[tid][3] = bx[3];
    u.p2.area[tid] = (bx[2] - bx[0]) * (bx[3] - bx[1]);
  }
  __syncthreads();
  double mx1 = 0, my1 = 0, mx2 = 0, my2 = 0, mar = 0;
  if (tid < TOPK) {
    mx1 = u.p2.box[tid][0]; my1 = u.p2.box[tid][1];
    mx2 = u.p2.box[tid][2]; my2 = u.p2.box[tid][3];
    mar = u.p2.area[tid];
  }
  keepL[tid] = (tid < TOPK) && (ssel[tid] > CONF_T);
  __syncthreads();
  for (int i = 0; i < TOPK; ++i) {
    int ki = keepL[i];
    if (ki && tid > i && tid < TOPK && keepL[tid]) {
      double lx = fmax(u.p2.box[i][0], mx1);
      double ly = fmax(u.p2.box[i][1], my1);
      double rx = fmin(u.p2.box[i][2], mx2);
      double ry = fmin(u.p2.box[i][3], my2);
      double iw = rx - lx; if (iw < 0.0) iw = 0.0;
      double ih = ry - ly; if (ih < 0.0) ih = 0.0;
      double inter = iw * ih;
      double iou = inter / (u.p2.area[i] + mar - inter + 1e-12);
      if (iou > NMS_T) keepL[tid] = 0;
    }
    __syncthreads();
  }
  bool kj = (tid < TOPK) && (keepL[tid] != 0);
  unsigned long long bal = __ballot((int)kj);
  int wave = tid >> 6, lane = tid & 63;
  if (lane == 0) wmask[wave] = bal;
  __syncthreads();
  int nk = 0;
#pragma unroll
  for (int w = 0; w < 4; ++w) nk += __popcll(wmask[w]);
  if (kj) {
    int pos = 0;
    for (int w = 0; w < wave; ++w) pos += __popcll(wmask[w]);
    pos += __popcll(bal & ((1ull << lane) - 1ull));
    float* o = outbase + (size_t)pos * 5;
    o[0] = (float)ssel[tid];
    o[1] = (float)u.p2.box[tid][0];
    o[2] = (float)u.p2.box[tid][1];
    o[3] = (float)u.p2.box[tid][2];
    o[4] = (float)u.p2.box[tid][3];
  }
  if (tid < TOPK && tid >= nk) {
    float* o = outbase + (size_t)tid * 5;
    o[0] = 0.0f; o[1] = 0.0f; o[2] = 0.0f; o[3] = 0.0f; o[4] = 0.0f;
  }
}

// ---------------------------------------------------------------------------
extern "C" void kernel_launch(void* const* d_in, const int* in_sizes, int n_in,
                              void* d_out, int out_size, void* d_ws, size_t ws_size,
                              hipStream_t stream) {
  const float* loc = (const float*)d_in[0];
  const float* conf = (const float*)d_in[1];
  const float* anchors = (const float*)d_in[2];
  float* out = (float*)d_out;

  const size_t WS_NEED = (size_t)NB * (NC - 1) * NA * sizeof(float);
  if (ws_size >= WS_NEED) {
    float* scores = (float*)d_ws;
    k_prep<<<(NB * NA) / 256, 256, 0, stream>>>(conf, scores);
    k_fast<<<NB * NC, 256, 0, stream>>>(loc, conf, anchors, scores, out);
  } else {
    k_main_nf<<<NB * NC, 256, 0, stream>>>(loc, conf, anchors, out);
  }
}